// Round 9
// baseline (959.408 us; speedup 1.0000x reference)
//
#include <hip/hip_runtime.h>
#include <math.h>

#define H 8
#define D 32
// MESSAGE_DIM = H*D = 256

typedef float f32x4 __attribute__((ext_vector_type(4)));

__device__ __forceinline__ float dot4(f32x4 a, f32x4 b) {
    return a.x * b.x + a.y * b.y + a.z * b.z + a.w * b.w;
}

// Pass 0 (fused): zero s[] AND compute xw[n,h] = x_e[n,h,:].w2[h].
// The xw hoist (R7, -140us) cut the per-edge gather from 1KB to 32B.
// Wave-per-node: lane = h*8+j, coalesced 1KB row load, 3-level shfl reduce.
__global__ __launch_bounds__(256) void aew_xw_kernel(
    const float* __restrict__ x_e,
    const float* __restrict__ weight,
    float*       __restrict__ xw,
    float*       __restrict__ s,
    int N)
{
    const int NH = N * H;
    for (int i = blockIdx.x * blockDim.x + threadIdx.x; i < NH;
         i += gridDim.x * blockDim.x) {
        s[i] = 0.0f;
    }

    const int lane = threadIdx.x & 63;
    const int h = lane >> 3;
    const int j = lane & 7;
    const int wavesPerBlock = blockDim.x >> 6;
    const int wave = blockIdx.x * wavesPerBlock + (threadIdx.x >> 6);
    const int nWaves = gridDim.x * wavesPerBlock;

    const f32x4 w2 = *(const f32x4*)(weight + h * 64 + 32 + j * 4);

    for (int n = wave; n < N; n += nWaves) {
        f32x4 xv = *((const f32x4*)(x_e + (size_t)n * 256) + lane);
        float d = dot4(xv, w2);
        d += __shfl_xor(d, 1);
        d += __shfl_xor(d, 2);
        d += __shfl_xor(d, 4);
        if (j == 0) xw[(size_t)n * H + h] = d;
    }
}

// Pass 1: WAVE-PER-EDGE (grid-stride). lane = h*8+j covers message chunk
// [h*32+j*4 .. +3]: one 1KB fully-coalesced load per edge. Score = dot(m,w1)
// (3 shfl reduce) + xw[t,h] (32B gather, prefetched one iteration ahead).
// LeakyReLU, exp, atomicAdd into s ONLY — ex is no longer materialized
// (R9: output recomputes it from the message row it already holds; saves the
// 51MB scattered ex write here + 51MB read in pass 2).
// Softmax max-pass dropped (shift-invariant; scores bounded ~|7|).
__global__ __launch_bounds__(256) void aew_score_kernel(
    const int*   __restrict__ target,
    const float* __restrict__ message,
    const float* __restrict__ xw,
    const float* __restrict__ weight,
    float*       __restrict__ s,
    int E)
{
    const int lane = threadIdx.x & 63;
    const int h = lane >> 3;
    const int j = lane & 7;
    const int wavesPerBlock = blockDim.x >> 6;
    const int wave = blockIdx.x * wavesPerBlock + (threadIdx.x >> 6);
    const int nWaves = gridDim.x * wavesPerBlock;

    const f32x4 w1 = *(const f32x4*)(weight + h * 64 + j * 4);

    int e = wave;
    int t = (e < E) ? target[e] : 0;
    float xwv = (e < E) ? xw[(size_t)t * H + h] : 0.0f;
    for (; e < E; e += nWaves) {
        // prefetch next edge's target + xw (breaks the serial addr chain)
        const int en = e + nWaves;
        int tn = (en < E) ? target[en] : 0;
        float xwn = (en < E) ? xw[(size_t)tn * H + h] : 0.0f;

        f32x4 mv = *((const f32x4*)(message + (size_t)e * 256) + lane);
        float d = dot4(mv, w1);
        d += __shfl_xor(d, 1);
        d += __shfl_xor(d, 2);
        d += __shfl_xor(d, 4);
        float p = d + xwv;
        float a = (p >= 0.0f) ? p : 0.1f * p;  // LeakyReLU(0.1)
        float ea = __expf(a);
        if (j == 0) {
            atomicAdd(&s[(size_t)t * H + h], ea);
        }
        t = tn; xwv = xwn;
    }
}

// Pass 2: WAVE-PER-EDGE (same lane layout as pass 1; a 64-lane wave holds the
// whole 256-float row). Recompute ea from the row in registers (bit-identical
// to pass 1: same inputs, same ops), then out = m * ea/max(s[t],1e-16).
// nt on the big streams: lines fully consumed within one wave instr; keeps
// s/xw L2/L3-resident.
__global__ __launch_bounds__(256) void aew_output_kernel(
    const int*   __restrict__ target,
    const float* __restrict__ message,
    const float* __restrict__ xw,
    const float* __restrict__ weight,
    const float* __restrict__ s,
    float*       __restrict__ out,
    int E)
{
    const int lane = threadIdx.x & 63;
    const int h = lane >> 3;
    const int j = lane & 7;
    const int wavesPerBlock = blockDim.x >> 6;
    const int wave = blockIdx.x * wavesPerBlock + (threadIdx.x >> 6);
    const int nWaves = gridDim.x * wavesPerBlock;

    const f32x4 w1 = *(const f32x4*)(weight + h * 64 + j * 4);

    int e = wave;
    int t = (e < E) ? target[e] : 0;
    float xwv = (e < E) ? xw[(size_t)t * H + h] : 0.0f;
    float sv  = (e < E) ? s[(size_t)t * H + h]  : 1.0f;
    for (; e < E; e += nWaves) {
        // prefetch next edge's target + xw + s
        const int en = e + nWaves;
        int tn = (en < E) ? target[en] : 0;
        float xwn = (en < E) ? xw[(size_t)tn * H + h] : 0.0f;
        float svn = (en < E) ? s[(size_t)tn * H + h]  : 1.0f;

        const f32x4* mrow = (const f32x4*)(message + (size_t)e * 256);
        f32x4 mv = __builtin_nontemporal_load(mrow + lane);
        float d = dot4(mv, w1);
        d += __shfl_xor(d, 1);
        d += __shfl_xor(d, 2);
        d += __shfl_xor(d, 4);
        float p = d + xwv;
        float a = (p >= 0.0f) ? p : 0.1f * p;  // LeakyReLU(0.1)
        float ea = __expf(a);
        float sc = ea / fmaxf(sv, 1e-16f);
        f32x4 o = mv * sc;
        __builtin_nontemporal_store(o, ((f32x4*)(out + (size_t)e * 256)) + lane);
        t = tn; xwv = xwn; sv = svn;
    }
}

extern "C" void kernel_launch(void* const* d_in, const int* in_sizes, int n_in,
                              void* d_out, int out_size, void* d_ws, size_t ws_size,
                              hipStream_t stream) {
    // inputs: source(E), target(E), message(E*256), x_e(N*256), weight(8*64)
    const int*   target  = (const int*)d_in[1];
    const float* message = (const float*)d_in[2];
    const float* x_e     = (const float*)d_in[3];
    const float* weight  = (const float*)d_in[4];
    float* out = (float*)d_out;

    const int E = in_sizes[1];
    const int N = in_sizes[3] / 256;

    // ws layout: s (N*H f32) | xw (N*H f32)
    float* s  = (float*)d_ws;
    float* xw = s + (size_t)N * H;

    aew_xw_kernel<<<1024, 256, 0, stream>>>(x_e, weight, xw, s, N);
    // 2048 blocks x 256 threads = 8192 waves, grid-stride over E edges.
    aew_score_kernel<<<2048, 256, 0, stream>>>(target, message, xw, weight, s, E);
    aew_output_kernel<<<2048, 256, 0, stream>>>(target, message, xw, weight, s, out, E);
}

// Round 10
// 869.406 us; speedup vs baseline: 1.1035x; 1.1035x over previous
//
#include <hip/hip_runtime.h>
#include <math.h>

#define H 8
#define D 32
// MESSAGE_DIM = H*D = 256

typedef float f32x4 __attribute__((ext_vector_type(4)));

__device__ __forceinline__ float dot4(f32x4 a, f32x4 b) {
    return a.x * b.x + a.y * b.y + a.z * b.z + a.w * b.w;
}

__global__ void aew_init_kernel(float* __restrict__ s, int n) {
    int i = blockIdx.x * blockDim.x + threadIdx.x;
    if (i < n) s[i] = 0.0f;
}

// Pass 0: xw[n,h] = x_e[n,h,:].w2[h]  — hoists the edge-independent half of
// the score out of the per-edge loop (R7: cut the per-edge x_e gather from
// 1KB to a 32B read of a 3.2MB L2-resident table; -140us).
// Wave-per-node: lane = h*8+j, coalesced 1KB row load, 3-level shfl reduce.
__global__ __launch_bounds__(256) void aew_xw_kernel(
    const float* __restrict__ x_e,
    const float* __restrict__ weight,
    float*       __restrict__ xw,
    int N)
{
    const int lane = threadIdx.x & 63;
    const int h = lane >> 3;
    const int j = lane & 7;
    const int wavesPerBlock = blockDim.x >> 6;
    const int wave = blockIdx.x * wavesPerBlock + (threadIdx.x >> 6);
    const int nWaves = gridDim.x * wavesPerBlock;

    const f32x4 w2 = *(const f32x4*)(weight + h * 64 + 32 + j * 4);

    for (int n = wave; n < N; n += nWaves) {
        f32x4 xv = *((const f32x4*)(x_e + (size_t)n * 256) + lane);
        float d = dot4(xv, w2);
        d += __shfl_xor(d, 1);
        d += __shfl_xor(d, 2);
        d += __shfl_xor(d, 4);
        if (j == 0) xw[(size_t)n * H + h] = d;
    }
}

// Pass 1: WAVE-PER-EDGE (grid-stride). lane = h*8+j covers message chunk
// [h*32+j*4 .. +3]: one 1KB fully-coalesced nt load per edge. Score =
// dot(m,w1) (3 shfl reduce) + xw[t,h] (32B L2 gather, prefetched one
// iteration ahead). LeakyReLU, exp, write ex, atomicAdd s.
// Softmax max-pass dropped (shift-invariant; scores bounded ~|7|).
// History: (e,h)-per-thread was transaction-bound (R4); pairing/2x-ILP
// neutral (R6); cached-vs-nt neutral (R8); recompute-in-output regressed
// (R9). This shape is the measured optimum (~350us, ~5 TB/s pure-read).
__global__ __launch_bounds__(256) void aew_score_kernel(
    const int*   __restrict__ target,
    const float* __restrict__ message,
    const float* __restrict__ xw,
    const float* __restrict__ weight,
    float*       __restrict__ ex,
    float*       __restrict__ s,
    int E)
{
    const int lane = threadIdx.x & 63;
    const int h = lane >> 3;
    const int j = lane & 7;
    const int wavesPerBlock = blockDim.x >> 6;
    const int wave = blockIdx.x * wavesPerBlock + (threadIdx.x >> 6);
    const int nWaves = gridDim.x * wavesPerBlock;

    const f32x4 w1 = *(const f32x4*)(weight + h * 64 + j * 4);

    int e = wave;
    int t = (e < E) ? target[e] : 0;
    float xwv = (e < E) ? xw[(size_t)t * H + h] : 0.0f;
    for (; e < E; e += nWaves) {
        // prefetch next edge's target + xw (breaks the serial addr chain)
        const int en = e + nWaves;
        int tn = (en < E) ? target[en] : 0;
        float xwn = (en < E) ? xw[(size_t)tn * H + h] : 0.0f;

        // message: streaming; each line fully consumed by one wave instr -> nt
        // spares L2/L3 for xw/s tables.
        f32x4 mv = __builtin_nontemporal_load((const f32x4*)(message + (size_t)e * 256) + lane);
        float d = dot4(mv, w1);
        d += __shfl_xor(d, 1);
        d += __shfl_xor(d, 2);
        d += __shfl_xor(d, 4);
        float p = d + xwv;
        float a = (p >= 0.0f) ? p : 0.1f * p;  // LeakyReLU(0.1)
        float ea = __expf(a);
        if (j == 0) {
            ex[(size_t)e * H + h] = ea;
            atomicAdd(&s[(size_t)t * H + h], ea);
        }
        t = tn; xwv = xwn;
    }
}

// Pass 2: flat f32x4 elementwise: out = message * (ex / max(s[target],1e-16)).
// One load -> scalar multiply -> one store, NO cross-lane ops: this shape
// sustains ~7 TB/s mixed r+w (R9's recompute variant with a reduce chain
// between load and store regressed 82us). nt keeps the 3.3 GB stream from
// evicting ex/s.
__global__ __launch_bounds__(256) void aew_output_kernel(
    const int*   __restrict__ target,
    const float* __restrict__ message,
    const float* __restrict__ ex,
    const float* __restrict__ s,
    float*       __restrict__ out,
    int n4)
{
    int i4 = blockIdx.x * blockDim.x + threadIdx.x;
    if (i4 >= n4) return;
    int e = i4 >> 6;
    int h = (i4 & 63) >> 3;
    int t = target[e];
    float sc = ex[e * H + h] / fmaxf(s[t * H + h], 1e-16f);
    f32x4 mv = __builtin_nontemporal_load(((const f32x4*)message) + i4);
    f32x4 o = mv * sc;
    __builtin_nontemporal_store(o, ((f32x4*)out) + i4);
}

extern "C" void kernel_launch(void* const* d_in, const int* in_sizes, int n_in,
                              void* d_out, int out_size, void* d_ws, size_t ws_size,
                              hipStream_t stream) {
    // inputs: source(E), target(E), message(E*256), x_e(N*256), weight(8*64)
    const int*   target  = (const int*)d_in[1];
    const float* message = (const float*)d_in[2];
    const float* x_e     = (const float*)d_in[3];
    const float* weight  = (const float*)d_in[4];
    float* out = (float*)d_out;

    const int E = in_sizes[1];
    const int N = in_sizes[3] / 256;
    const int NH = N * H;

    // ws layout: ex (E*H f32) | s (N*H f32) | xw (N*H f32)
    float* ex = (float*)d_ws;
    float* s  = ex + (size_t)E * H;
    float* xw = s + (size_t)NH;

    aew_init_kernel<<<(NH + 255) / 256, 256, 0, stream>>>(s, NH);
    aew_xw_kernel<<<1024, 256, 0, stream>>>(x_e, weight, xw, N);
    // 2048 blocks x 256 threads = 8192 waves, grid-stride over E edges.
    aew_score_kernel<<<2048, 256, 0, stream>>>(target, message, xw, weight, ex, s, E);
    const int n4 = E * 64;  // E*256/4 f32x4 elements
    aew_output_kernel<<<(n4 + 255) / 256, 256, 0, stream>>>(target, message, ex, s, out, n4);
}